// Round 12
// baseline (2778.618 us; speedup 1.0000x reference)
//
#include <hip/hip_runtime.h>
#include <hip/hip_bf16.h>

#define DIMD 256
#define DIMC 64
#define WRS  40   // padded router-w row stride (floats) -> g*8 hits distinct banks

typedef __attribute__((ext_vector_type(8))) __bf16 bf16x8;
typedef __attribute__((ext_vector_type(4))) float f32x4;

__global__ __launch_bounds__(256, 4) void tree_node_kernel(
    const float* __restrict__ x,
    const float* __restrict__ w_router,
    const float* __restrict__ b_router,
    const float* __restrict__ w_left,
    const float* __restrict__ b_left,
    const float* __restrict__ w_right,
    const float* __restrict__ b_right,
    float* __restrict__ out,
    int iters)
{
    __shared__ float wr_s[8 * WRS];     // router weights, padded [s][40]
    __shared__ float bb_s[2 * DIMC];    // biases left|right

    const int tid  = threadIdx.x;
    const int lane = tid & 63;
    const int wave = tid >> 6;
    const int g    = lane >> 4;         // k-group 0..3
    const int m    = lane & 15;         // token within tile (B-operand col)
    const int colbase = wave * 16;      // this wave's 16 output cols

    // dense-front mapping: 16-token tile(it) = it*gridDim.x + blockIdx.x.
    // All 4 waves of a block stream the SAME 16 token rows (4 col-groups):
    // redundant load ISSUE, but L1/L2-served; HBM reads stay 1x.
    const size_t row_stride = (size_t)gridDim.x * 16;
    size_t row0 = (size_t)blockIdx.x * 16;

    // rolling 4-step load ring (32 VGPR); slot index always compile-time
    f32x4 px[4][2];

#define ISSUE_STEP(rowbase, s_, slot)                                         \
    {                                                                         \
        const float* p = x + ((rowbase) + m) * DIMD + (s_) * 32 + g * 8;      \
        px[slot][0] = *(const f32x4*)(p);                                     \
        px[slot][1] = *(const f32x4*)(p + 4);                                 \
    }

    // prefill tile0 steps 0..3 (loads fly while prologue runs)
    ISSUE_STEP(row0, 0, 0)
    ISSUE_STEP(row0, 1, 1)
    ISSUE_STEP(row0, 2, 2)
    ISSUE_STEP(row0, 3, 3)

    // ---- prologue: W fragments -> registers (A-operand, verified in v11) ----
    bf16x8 wL[8], wR[8];
#pragma unroll
    for (int s = 0; s < 8; ++s)
#pragma unroll
        for (int j = 0; j < 8; ++j) {
            const int k = s * 32 + g * 8 + j;
            wL[s][j] = (__bf16)w_left[k * DIMC + colbase + m];
            wR[s][j] = (__bf16)w_right[k * DIMC + colbase + m];
        }
    if (tid < DIMC) { bb_s[tid] = b_left[tid]; bb_s[DIMC + tid] = b_right[tid]; }
    {   // padded router weights: [s][q], q = 0..31
        const int s = tid >> 5, q = tid & 31;
        wr_s[s * WRS + q] = w_router[s * 32 + q];
    }
    const float brout = b_router[0];

    __syncthreads();   // the ONLY barrier (publishes wr_s / bb_s)

    // consume step s: fp64 router partial + cvt->bf16 frag + 2 MFMA;
    // then reissue the slot for step s+4 (same tile s<4, next tile s>=4).
#define STEP(s_, rowbase_next, s_next, doissue)                               \
    {                                                                         \
        const f32x4 wlo = *(const f32x4*)&wr_s[(s_) * WRS + g * 8];           \
        const f32x4 whi = *(const f32x4*)&wr_s[(s_) * WRS + g * 8 + 4];       \
        bf16x8 a;                                                             \
        _Pragma("unroll")                                                     \
        for (int j = 0; j < 4; ++j) {                                         \
            a[j]     = (__bf16)px[(s_) & 3][0][j];                            \
            a[j + 4] = (__bf16)px[(s_) & 3][1][j];                            \
            racc += (double)px[(s_) & 3][0][j] * (double)wlo[j]               \
                  + (double)px[(s_) & 3][1][j] * (double)whi[j];              \
        }                                                                     \
        if (doissue) ISSUE_STEP(rowbase_next, s_next, (s_) & 3)               \
        accL = __builtin_amdgcn_mfma_f32_16x16x32_bf16(wL[s_], a, accL, 0, 0, 0); \
        accR = __builtin_amdgcn_mfma_f32_16x16x32_bf16(wR[s_], a, accR, 0, 0, 0); \
    }

    for (int it = 0; it < iters; ++it) {
        const size_t rnext = row0 + row_stride;
        const bool   more  = (it + 1 < iters);
        f32x4 accL = {0.f,0.f,0.f,0.f}, accR = {0.f,0.f,0.f,0.f};
        double racc = 0.0;

        STEP(0, row0,  4, true)    // consume (it,0), issue (it,4)
        STEP(1, row0,  5, true)
        STEP(2, row0,  6, true)
        STEP(3, row0,  7, true)
        STEP(4, rnext, 0, more)    // consume (it,4), issue (it+1,0)
        STEP(5, rnext, 1, more)
        STEP(6, rnext, 2, more)
        STEP(7, rnext, 3, more)

        // router: reduce fp64 partials over the 4 g-lanes of token m
        racc += __shfl_xor(racc, 16);
        racc += __shfl_xor(racc, 32);
        const bool leftsel = ((float)(racc + (double)brout) > 0.0f);

        // epilogue: select child + bias, direct 16B store (wave writes 64B/row)
        const f32x4 bl = *(const f32x4*)&bb_s[colbase + g * 4];
        const f32x4 br = *(const f32x4*)&bb_s[DIMC + colbase + g * 4];
        f32x4 ov;
#pragma unroll
        for (int r = 0; r < 4; ++r)
            ov[r] = leftsel ? (accL[r] + bl[r]) : (accR[r] + br[r]);
        *(f32x4*)(out + (row0 + m) * DIMC + colbase + g * 4) = ov;

        row0 = rnext;
    }
#undef ISSUE_STEP
#undef STEP
}

extern "C" void kernel_launch(void* const* d_in, const int* in_sizes, int n_in,
                              void* d_out, int out_size, void* d_ws, size_t ws_size,
                              hipStream_t stream) {
    const float* x        = (const float*)d_in[0];
    const float* w_router = (const float*)d_in[1];
    const float* b_router = (const float*)d_in[2];
    const float* w_left   = (const float*)d_in[3];
    const float* b_left   = (const float*)d_in[4];
    const float* w_right  = (const float*)d_in[5];
    const float* b_right  = (const float*)d_in[6];
    float* out = (float*)d_out;

    const int n_tok = in_sizes[0] / DIMD;   // 1,048,576
    const int grid  = 1024;                 // exactly resident: 4 blocks/CU
    const int iters = n_tok / (grid * 16);  // 64

    tree_node_kernel<<<grid, 256, 0, stream>>>(
        x, w_router, b_router, w_left, b_left, w_right, b_right, out, iters);
}

// Round 13
// 286.862 us; speedup vs baseline: 9.6863x; 9.6863x over previous
//
#include <hip/hip_runtime.h>
#include <hip/hip_bf16.h>

#define DIMD 256
#define DIMC 64
#define RPT  16   // rows per tile

typedef __attribute__((ext_vector_type(8))) __bf16 bf16x8;
typedef __attribute__((ext_vector_type(4))) __bf16 bf16x4;
typedef __attribute__((ext_vector_type(4))) float f32x4;

// Loop-carried register pin: forces the value to LIVE IN VGPRs across
// iterations -- the compiler can no longer rematerialize it by re-loading
// from global memory inside the loop (v12's VGPR_Count=64 proved it does).
#define PIN(v) asm volatile("" : "+v"(v))

__global__ __launch_bounds__(256, 4) void tree_node_kernel(
    const float* __restrict__ x,
    const float* __restrict__ w_router,
    const float* __restrict__ b_router,
    const float* __restrict__ w_left,
    const float* __restrict__ b_left,
    const float* __restrict__ w_right,
    const float* __restrict__ b_right,
    float* __restrict__ out,
    int iters)
{
    __shared__ __bf16 xb16[2][RPT * DIMD];                  // 2 x 8 KB, swizzled
    __shared__ float  wr_s[DIMD];                           // 1 KB router w
    __shared__ int    mask_lds[2][RPT] __attribute__((aligned(16)));

    const int tid  = threadIdx.x;
    const int lane = tid & 63;
    const int wave = tid >> 6;
    const int g    = lane >> 4;   // k-group 0..3 (MFMA)
    const int m    = lane & 15;   // swapped operands: m = TOKEN row
    const int srow = tid >> 4;    // staging row 0..15
    const int sm   = tid & 15;    // staging chunk 0..15

    // ---- prologue: W fragments -> registers (MFMA *A* operand, w^T tile):
    //      lane(g,m) holds w[k=s*32+g*8+j][wave*16+m] ----
    const int colbase = wave * 16;
    bf16x8 bL[8], bR[8];
#pragma unroll
    for (int s = 0; s < 8; ++s)
#pragma unroll
        for (int j = 0; j < 8; ++j) {
            const int k = s * 32 + g * 8 + j;
            bL[s][j] = (__bf16)w_left[k * DIMC + colbase + m];
            bR[s][j] = (__bf16)w_right[k * DIMC + colbase + m];
        }
    // per-lane biases for this lane's 4 output classes (cols wave*16+g*4+r)
    float biasL4[4], biasR4[4];
#pragma unroll
    for (int r = 0; r < 4; ++r) {
        biasL4[r] = b_left[colbase + g * 4 + r];
        biasR4[r] = b_right[colbase + g * 4 + r];
    }
    const float brout = b_router[0];
    wr_s[tid] = w_router[tid];

    // GRID-STRIDED tile mapping (dense moving front)
    const size_t row_base   = (size_t)blockIdx.x * RPT;
    const size_t row_stride = (size_t)gridDim.x * RPT;
#define ROW0(itile) (row_base + (size_t)(itile) * row_stride)

    __syncthreads();   // wr_s ready

    f32x4 sx[4];       // staged f32 (one 16-float slice of one row)

#define ISSUE(itile)                                                          \
    {                                                                         \
        const float* xr = x + (ROW0(itile) + srow) * DIMD + sm * 4;           \
        _Pragma("unroll")                                                     \
        for (int j = 0; j < 4; ++j) sx[j] = *(const f32x4*)(xr + j * 64);     \
    }

    // consume: fp64 router partial + cvt bf16 + swizzled LDS write + mask.
    // swizzle: 16B piece p -> p ^ (row&7); same involution on B-frag reads.
#define CONSUME(itile)                                                        \
    {                                                                         \
        const int slot = (itile) & 1;                                         \
        double racc = 0.0;                                                    \
        const int rx = srow & 7;                                              \
        _Pragma("unroll")                                                     \
        for (int j = 0; j < 4; ++j) {                                         \
            const f32x4 wv = *(const f32x4*)&wr_s[sm * 4 + j * 64];           \
            bf16x4 v;                                                         \
            _Pragma("unroll")                                                 \
            for (int e = 0; e < 4; ++e) {                                     \
                racc += (double)sx[j][e] * (double)wv[e];                     \
                v[e] = (__bf16)sx[j][e];                                      \
            }                                                                 \
            const int p = (sm >> 1) + 8 * j;                                  \
            *(bf16x4*)&xb16[slot][srow * DIMD +                               \
                (((p ^ rx) << 3) | ((sm & 1) << 2))] = v;                     \
        }                                                                     \
        racc += __shfl_xor(racc, 1);                                          \
        racc += __shfl_xor(racc, 2);                                          \
        racc += __shfl_xor(racc, 4);                                          \
        racc += __shfl_xor(racc, 8);                                          \
        if (sm == 0)                                                          \
            mask_lds[slot][srow] =                                            \
                ((float)(racc + (double)brout) > 0.0f) ? 1 : 0;               \
    }

    // ---- prologue staging: tile 0 staged, tile 1 loads left IN FLIGHT ----
    ISSUE(0);
    CONSUME(0);
    ISSUE(1);
    asm volatile("s_waitcnt lgkmcnt(0)" ::: "memory");
    __builtin_amdgcn_s_barrier();

    for (int it = 0; it < iters; ++it) {
        // ---- 0) PIN weight fragments: loop-carried "+v" ties keep all 16
        //         fragments resident in VGPRs (no in-loop reload possible) ----
#pragma unroll
        for (int s = 0; s < 8; ++s) { PIN(bL[s]); PIN(bR[s]); }

        // ---- 1) MFMA tile it, operand-swapped: D = (w^T-tile)x(x^T-tile).
        //         acc[r] = out[token m][class wave*16+g*4+r] ----
        const __bf16* xb = &xb16[it & 1][0];
        const int lm = mask_lds[it & 1][m];      // this lane's token mask
        f32x4 accL = {0.f,0.f,0.f,0.f}, accR = {0.f,0.f,0.f,0.f};
        const int axr = m & 7;
#pragma unroll
        for (int s = 0; s < 8; ++s) {
            const int p = s * 4 + g;
            const bf16x8 a = *(const bf16x8*)&xb[m * DIMD + ((p ^ axr) << 3)];
            accL = __builtin_amdgcn_mfma_f32_16x16x32_bf16(bL[s], a, accL, 0, 0, 0);
            accR = __builtin_amdgcn_mfma_f32_16x16x32_bf16(bR[s], a, accR, 0, 0, 0);
        }

        // ---- 2) select child + bias, direct 16B store from acc ----
        {
            f32x4 ov;
#pragma unroll
            for (int r = 0; r < 4; ++r)
                ov[r] = lm ? (accL[r] + biasL4[r]) : (accR[r] + biasR4[r]);
            *(f32x4*)(out + (ROW0(it) + m) * DIMC + colbase + g * 4) = ov;
        }

        // ---- 3) consume tile it+1 (loads issued LAST iter; counted vmcnt —
        //         the step-2 store is newer in the FIFO, stays in flight) ----
        if (it + 1 < iters) CONSUME(it + 1);

        // ---- 4) issue tile it+2 (loads stay in flight ACROSS the barrier) ----
        if (it + 2 < iters) ISSUE(it + 2);

        // ---- 5) barrier: lgkm-only (publishes xb16[it+1] + mask).
        //         NO vmcnt drain: loads(it+2) + store(it) stay in flight ----
        asm volatile("s_waitcnt lgkmcnt(0)" ::: "memory");
        __builtin_amdgcn_s_barrier();
    }
#undef ISSUE
#undef CONSUME
#undef ROW0
}

extern "C" void kernel_launch(void* const* d_in, const int* in_sizes, int n_in,
                              void* d_out, int out_size, void* d_ws, size_t ws_size,
                              hipStream_t stream) {
    const float* x        = (const float*)d_in[0];
    const float* w_router = (const float*)d_in[1];
    const float* b_router = (const float*)d_in[2];
    const float* w_left   = (const float*)d_in[3];
    const float* b_left   = (const float*)d_in[4];
    const float* w_right  = (const float*)d_in[5];
    const float* b_right  = (const float*)d_in[6];
    float* out = (float*)d_out;

    const int n_tok = in_sizes[0] / DIMD;   // 1,048,576
    const int grid  = 1024;                 // 4 blocks/CU x 256 CU (LDS ~18 KB)
    const int iters = n_tok / (grid * RPT); // 64

    tree_node_kernel<<<grid, 256, 0, stream>>>(
        x, w_router, b_router, w_left, b_left, w_right, b_right, out, iters);
}